// Round 15
// baseline (31.333 us; speedup 1.0000x reference)
//
#include <hip/hip_runtime.h>
#include <cstdint>
#include <cstddef>

// BAP: out0[b,m,c] = (1/HW) * sum_k feat[b,c,k] * sigmoid(raw[b,m,k])
//      out1[b,m,k] = sigmoid(raw[b,m,k])
// B=16, C=1024, M=32, K=H*W=1024.
// R14: R13's self-timing proved bap loop = 12.7us (80% achievable HBM);
// the other ~10us was sigmoid kernel + 2x launch overhead. Fix: SINGLE
// fused kernel. A-frags load raw fp32 (L2-hot) + sigma on the fly (same
// __expf+RNE ops as before, bit-identical); out1 written by designated
// block rows after the loop. Counted-vmcnt ring kept (af 2-ahead in 2
// slots, stage 3-ahead in 4-deep LDS ring; audited vmcnt 16/16/16/16/16/
// 16/12/0). Issues after compute(s): af slot WAR protected by in-order
// issue + asm reg dependency.

#define BB 16
#define CC 1024
#define MM 32
#define HW 1024

#define TCR 32               // c-rows per block
#define TKF 128              // feat k per stage -> 32 x 16B slots per row
#define NSTF (HW / TKF)      // 8 stages
#define ND 4                 // feat ring depth

typedef __attribute__((ext_vector_type(4))) float f32x4;
typedef __attribute__((ext_vector_type(8))) short s16x8;

__device__ inline short bf16rne(float x)
{
    uint32_t u = __builtin_bit_cast(uint32_t, x);
    u = (u + 0x7FFFu + ((u >> 16) & 1u)) >> 16;
    return (short)u;
}

__device__ inline s16x8 cvt8(f32x4 lo, f32x4 hi)
{
    s16x8 r;
#pragma unroll
    for (int j = 0; j < 4; ++j) {
        r[j]     = bf16rne(lo[j]);
        r[4 + j] = bf16rne(hi[j]);
    }
    return r;
}

__device__ inline f32x4 sig4(f32x4 v)
{
    f32x4 o;
#pragma unroll
    for (int j = 0; j < 4; ++j)
        o[j] = 1.0f / (1.0f + __expf(-v[j]));
    return o;
}

// async global->LDS, 16B/lane, wave-uniform LDS base (HW: base + lane*16)
__device__ inline void gld_lds16(const void* g, void* l)
{
    __builtin_amdgcn_global_load_lds(
        (const __attribute__((address_space(1))) void*)g,
        (__attribute__((address_space(3))) void*)l, 16, 0, 0);
}

// ---------------- fused kernel ----------------
// Grid 512 = 32 c-tiles x 16 b (b = low 4 bits -> same-b blocks share XCD;
// raw[b] 128KB stays L2-hot). 256 threads = 4 waves; wave w = (mt, c2).
// feat ring fsh[4][32][128] (64 KB -> 2 blocks/CU), XOR-slot swizzle via
// pre-swizzled gload_lds source (rule #21). A-frags: asm global_load_dwordx4
// pairs from raw, sigma+cvt in compute (bit-identical to old ws path).
__global__ __launch_bounds__(256) void bap_fused(
    const float* __restrict__ feat,   // [B][C][HW] fp32
    const float* __restrict__ raw,    // [B][M][HW] fp32
    float* __restrict__ out0,         // [B][M][C]
    float* __restrict__ out1)         // [B][M][HW] = sigmoid(raw)
{
    __shared__ float fsh[ND][TCR][TKF];      // 64 KB

    const int t  = threadIdx.x;
    const int w  = t >> 6;                   // wave 0..3
    const int l  = t & 63;
    const int b  = blockIdx.x & 15;
    const int ct = blockIdx.x >> 4;          // 0..31
    const int cbase = ct * TCR;

    const int lrow  = l >> 5;                // 0..1 (row within 2-row chunk)
    const int lslot = l & 31;                // 16B slot within 512B row

    const float* fbase = feat + (size_t)(b * CC + cbase) * HW;

    // feat stage s -> ring buf s&3: 4 gld_lds16/lane, 2 rows each (16 KB)
    auto stage = [&](int s) {
        const int nb = s & (ND - 1);
        const int k0 = s * TKF;
#pragma unroll
        for (int i = 0; i < 4; ++i) {
            int r0  = w * 8 + i * 2;                  // wave-uniform
            int row = r0 + lrow;
            int sg  = lslot ^ (row & 15);             // source-side swizzle
            gld_lds16(fbase + (size_t)row * HW + k0 + sg * 4,
                      &fsh[nb][r0][0]);
        }
    };

    // MFMA geometry (variant 0, R7/R8/R10-proven)
    const int r  = l & 15;
    const int q  = l >> 4;
    const int mt = w >> 1;                   // 0..1
    const int c2 = w & 1;                    // 0..1
    const int arow = mt * 16 + r;
    const int brow = c2 * 16 + r;            // brow & 15 == r
    const float* ap_raw = raw + (size_t)(b * MM + arow) * HW;

    // A-fragment raw fp32, 2 slots (64 VGPR), asm-pinned in the vmcnt FIFO.
    f32x4 afl[2][4], afh[2][4];
    auto load_af = [&](int s) {
        const int pb = s & 1;
#pragma unroll
        for (int ch = 0; ch < 4; ++ch) {
            const float* a = ap_raw + s * TKF + ch * 32 + q * 8;
            asm volatile("global_load_dwordx4 %0, %1, off"
                         : "=&v"(afl[pb][ch]) : "v"(a) : "memory");
            asm volatile("global_load_dwordx4 %0, %1, off offset:16"
                         : "=&v"(afh[pb][ch]) : "v"(a) : "memory");
        }
    };

    f32x4 acc = {0.f, 0.f, 0.f, 0.f};

    auto compute = [&](int s) {
        const int nb = s & (ND - 1);
        const int pb = s & 1;
#pragma unroll
        for (int ch = 0; ch < 4; ++ch) {              // four K=32 chunks
            const int S0 = ch * 8 + 2 * q;            // 16B slot of lo half
            f32x4 blo = *reinterpret_cast<const f32x4*>(
                &fsh[nb][brow][(S0 ^ r) * 4]);
            f32x4 bhi = *reinterpret_cast<const f32x4*>(
                &fsh[nb][brow][((S0 + 1) ^ r) * 4]);
            s16x8 af = cvt8(sig4(afl[pb][ch]), sig4(afh[pb][ch]));
            acc = __builtin_amdgcn_mfma_f32_16x16x32_bf16(
                      af, cvt8(blo, bhi), acc, 0, 0, 0);
        }
    };

    // ---- prologue FIFO: af0(8) st0(4) af1(8) st1(4) st2(4) = 28 ops ----
    load_af(0); stage(0);
    load_af(1); stage(1);
    stage(2);

    // ---- steady state: one barrier/iter, counted vmcnt (T4).
    // Audited: vmcnt(16) for s<=5 retires {af(s), st(s)}; 12 at s=6; 0 at 7.
    // Issues AFTER compute(s): af slot (s+2)&1 == s&1 (WAR safe, see header);
    // st(s+3) targets buf (s-1)&3, retired by this iter's barrier. ----
#pragma unroll
    for (int s = 0; s < NSTF; ++s) {
        if (s <= 5)      asm volatile("s_waitcnt vmcnt(16)" ::: "memory");
        else if (s == 6) asm volatile("s_waitcnt vmcnt(12)" ::: "memory");
        else             asm volatile("s_waitcnt vmcnt(0)"  ::: "memory");
        __builtin_amdgcn_sched_barrier(0);
        __builtin_amdgcn_s_barrier();
        compute(s);
        if (s + 2 < NSTF) load_af(s + 2);
        if (s + 3 < NSTF) stage(s + 3);
    }

    // ---- out1 duty: block (b,ct) writes sigma row ct of out1[b] ----
    {
        const float* rrow = raw  + (size_t)(b * MM + ct) * HW;
        float*       orow = out1 + (size_t)(b * MM + ct) * HW;
        f32x4 rv = reinterpret_cast<const f32x4*>(rrow)[t];
        reinterpret_cast<f32x4*>(orow)[t] = sig4(rv);
    }

    // ---- epilogue: D[reg] -> out0[b][mt*16+4q+reg][cbase + c2*16 + r] ----
    const float sc = 1.0f / (float)HW;
    float* p = out0 + (size_t)(b * MM) * CC + cbase + c2 * 16;
#pragma unroll
    for (int reg = 0; reg < 4; ++reg)
        p[(size_t)(mt * 16 + 4 * q + reg) * CC + r] = acc[reg] * sc;
}

extern "C" void kernel_launch(void* const* d_in, const int* in_sizes, int n_in,
                              void* d_out, int out_size, void* d_ws, size_t ws_size,
                              hipStream_t stream)
{
    const float* feat = (const float*)d_in[0];   // [16,1024,32,32]
    const float* raw  = (const float*)d_in[1];   // [16,32,32,32]
    float* out0 = (float*)d_out;                           // [16,32,1024]
    float* out1 = out0 + (size_t)BB * MM * HW;             // [16,32,32,32]

    bap_fused<<<512, 256, 0, stream>>>(feat, raw, out0, out1);
}